// Round 4
// baseline (229.470 us; speedup 1.0000x reference)
//
#include <hip/hip_runtime.h>

// DotProductAttention B=2,H=16,S=2048,D=64 fp32. f16-MFMA flash attention.
// Round 4: 512 threads (8 waves x 16 q-rows) -> 16 waves/CU; P stride 68
// halves (136 B) -> all-32-bank P writes (2-way same-dword = free), b64 reads.

typedef _Float16 half8 __attribute__((ext_vector_type(8)));
typedef _Float16 half4 __attribute__((ext_vector_type(4)));
typedef float floatx4 __attribute__((ext_vector_type(4)));

constexpr int BQ = 128;
constexpr int BK = 64;
constexpr int DH = 64;
constexpr int SLEN = 2048;
constexpr int NT = SLEN / BK;
constexpr int THREADS = 512;
constexpr int PSTR = 68;      // halves per P row (136 B): quad stride = 8 banks

#define MFMA16(a, b, c) __builtin_amdgcn_mfma_f32_16x16x32_f16(a, b, c, 0, 0, 0)

struct SMem {
    union {
        float qstage[BQ * DH];                  // 32 KB, start only
        struct {
            _Float16 ks[BK * DH];               // 8 KB [key][d], granule swz g^(key&7)
            _Float16 vt[DH * BK];               // 8 KB [d][key], granule swz g^(d&7)
            _Float16 pw[8][16 * PSTR];          // 17.4 KB per-wave P [row][key]
        } s;
    } u;
};

__global__ __launch_bounds__(THREADS, 4)
void attn_f16_mfma(const float* __restrict__ Q, const float* __restrict__ K,
                   const float* __restrict__ V, float* __restrict__ Out,
                   const int* __restrict__ dkp)
{
    __shared__ SMem sm;

    const int tid  = threadIdx.x;
    const int wave = tid >> 6;
    const int lane = tid & 63;
    const int quad = lane >> 4;
    const int n16  = lane & 15;

    // XCD-aware decode: each head's K/V stays in one XCD's L2.
    const int id   = blockIdx.x;
    const int xcd  = id & 7;
    const int slot = id >> 3;
    const int head = xcd * 4 + (slot >> 4);
    const int qt   = slot & 15;

    const float scale2 = rsqrtf((float)(*dkp)) * 1.44269504088896340736f;

    const size_t headoff = (size_t)head * SLEN * DH;

    // ---- stage Q tile (fp32, swizzled), pull scaled f16 A-frags ----
    {
        const float4* Qg = (const float4*)(Q + headoff + (size_t)qt * BQ * DH);
        for (int i = tid; i < BQ * DH / 4; i += THREADS) {
            int row = i >> 4, g = i & 15;
            ((float4*)sm.u.qstage)[row * 16 + (g ^ (row & 15))] = Qg[i];
        }
    }
    __syncthreads();

    half8 qA[2];
    #pragma unroll
    for (int kd = 0; kd < 2; kd++) {
        int row = wave * 16 + n16;
        int g0 = kd * 8 + quad * 2;
        float4 a = ((const float4*)sm.u.qstage)[row * 16 + (g0 ^ (row & 15))];
        float4 b = ((const float4*)sm.u.qstage)[row * 16 + ((g0 + 1) ^ (row & 15))];
        half8 h;
        h[0] = (_Float16)(a.x * scale2); h[1] = (_Float16)(a.y * scale2);
        h[2] = (_Float16)(a.z * scale2); h[3] = (_Float16)(a.w * scale2);
        h[4] = (_Float16)(b.x * scale2); h[5] = (_Float16)(b.y * scale2);
        h[6] = (_Float16)(b.z * scale2); h[7] = (_Float16)(b.w * scale2);
        qA[kd] = h;
    }
    __syncthreads();   // qstage dead; LDS becomes ks/vt/pw

    const float* Kh = K + headoff;
    const float* Vh = V + headoff;

    // K prefetch: thread covers row s = tid>>3, d-granule g = tid&7 -> 2 float4.
    // V prefetch: thread covers d = lane, s-granule = wave -> 8 strided dwords
    //   (each j: 64 lanes read 256 contiguous bytes).
    const int ks_row = tid >> 3, ks_g = tid & 7;
    float4 kpref[2];
    float  vpref[8];
    {
        const float4* kp = (const float4*)Kh;
        kpref[0] = kp[ks_row * 16 + ks_g * 2];
        kpref[1] = kp[ks_row * 16 + ks_g * 2 + 1];
        #pragma unroll
        for (int j = 0; j < 8; j++)
            vpref[j] = Vh[(size_t)(wave * 8 + j) * 64 + lane];
    }

    floatx4 oacc[4];
    floatx4 lsum;
    const floatx4 fz = {0.f, 0.f, 0.f, 0.f};
    lsum = fz;
    #pragma unroll
    for (int cg = 0; cg < 4; cg++) oacc[cg] = fz;
    half8 ones;
    #pragma unroll
    for (int j = 0; j < 8; j++) ones[j] = (_Float16)1.0f;

    for (int kt = 0; kt < NT; ++kt) {
        __syncthreads();   // prev iteration's ks/vt reads done

        // ---- stage K: one b128 per thread, conflict-free (g^(s&7)) ----
        {
            float4 a = kpref[0], b = kpref[1];
            half8 h;
            h[0] = (_Float16)a.x; h[1] = (_Float16)a.y;
            h[2] = (_Float16)a.z; h[3] = (_Float16)a.w;
            h[4] = (_Float16)b.x; h[5] = (_Float16)b.y;
            h[6] = (_Float16)b.z; h[7] = (_Float16)b.w;
            *(half8*)&sm.u.s.ks[ks_row * 64 + ((ks_g ^ (ks_row & 7)) << 3)] = h;
        }
        // ---- stage V transposed: one b128 per thread, conflict-free (g^(d&7)) ----
        {
            half8 h;
            #pragma unroll
            for (int j = 0; j < 8; j++) h[j] = (_Float16)vpref[j];
            *(half8*)&sm.u.s.vt[lane * 64 + ((wave ^ (lane & 7)) << 3)] = h;
        }
        // issue next tile's global loads (overlap with compute)
        if (kt + 1 < NT) {
            const float4* kp = (const float4*)(Kh + (size_t)(kt + 1) * BK * DH);
            const float*  vp = Vh + (size_t)(kt + 1) * BK * DH;
            kpref[0] = kp[ks_row * 16 + ks_g * 2];
            kpref[1] = kp[ks_row * 16 + ks_g * 2 + 1];
            #pragma unroll
            for (int j = 0; j < 8; j++)
                vpref[j] = vp[(size_t)(wave * 8 + j) * 64 + lane];
        }
        __syncthreads();   // ks/vt visible

        // ---- K B-frags; S = Q K^T ----
        half8 kB[2][4];
        #pragma unroll
        for (int kd = 0; kd < 2; kd++)
            #pragma unroll
            for (int cg = 0; cg < 4; cg++) {
                int key = cg * 16 + n16;
                int g = (kd * 4 + quad) ^ (key & 7);
                kB[kd][cg] = *(const half8*)&sm.u.s.ks[key * 64 + (g << 3)];
            }
        floatx4 sC[4];
        #pragma unroll
        for (int cg = 0; cg < 4; cg++) {
            floatx4 c = MFMA16(qA[0], kB[0][cg], fz);
            sC[cg] = MFMA16(qA[1], kB[1][cg], c);
        }

        // ---- P = exp2(S) -> per-wave padded LDS ----
        // bank(quad,n16) = 8*quad + 8*cg + (n16>>1) + const -> 32 banks,
        // 2 lanes/bank in the same dword (free).
        _Float16* P = sm.u.s.pw[wave];
        #pragma unroll
        for (int cg = 0; cg < 4; cg++)
            #pragma unroll
            for (int r = 0; r < 4; r++) {
                int row = quad * 4 + r;
                int col = cg * 16 + n16;
                P[row * PSTR + col] = (_Float16)exp2f(sC[cg][r]);
            }

        // ---- P A-frags (intra-wave round trip; 2x b64, 8B-aligned) ----
        half8 pA[2];
        #pragma unroll
        for (int kd = 0; kd < 2; kd++) {
            const _Float16* base = &P[n16 * PSTR + kd * 32 + quad * 8];
            half4 lo = *(const half4*)base;
            half4 hi = *(const half4*)(base + 4);
            half8 h;
            h[0] = lo[0]; h[1] = lo[1]; h[2] = lo[2]; h[3] = lo[3];
            h[4] = hi[0]; h[5] = hi[1]; h[6] = hi[2]; h[7] = hi[3];
            pA[kd] = h;
        }
        // ---- V B-frags ----
        half8 vB[2][4];
        #pragma unroll
        for (int kd = 0; kd < 2; kd++)
            #pragma unroll
            for (int cg = 0; cg < 4; cg++) {
                int d = cg * 16 + n16;
                int g = (kd * 4 + quad) ^ (d & 7);
                vB[kd][cg] = *(const half8*)&sm.u.s.vt[d * 64 + (g << 3)];
            }

        // ---- row sums (ones-MFMA) and O += P V ----
        lsum = MFMA16(pA[0], ones, lsum);
        lsum = MFMA16(pA[1], ones, lsum);
        #pragma unroll
        for (int cg = 0; cg < 4; cg++) {
            oacc[cg] = MFMA16(pA[0], vB[0][cg], oacc[cg]);
            oacc[cg] = MFMA16(pA[1], vB[1][cg], oacc[cg]);
        }
    }

    // ---- epilogue: O / l, fp32 store ----
    float* Og = Out + headoff + (size_t)qt * BQ * DH;
    #pragma unroll
    for (int r = 0; r < 4; r++) {
        float inv = 1.0f / lsum[r];
        int row = wave * 16 + quad * 4 + r;
        #pragma unroll
        for (int cg = 0; cg < 4; cg++)
            Og[row * 64 + cg * 16 + n16] = oacc[cg][r] * inv;
    }
}

extern "C" void kernel_launch(void* const* d_in, const int* in_sizes, int n_in,
                              void* d_out, int out_size, void* d_ws, size_t ws_size,
                              hipStream_t stream) {
    const float* Q = (const float*)d_in[0];
    const float* K = (const float*)d_in[1];
    const float* V = (const float*)d_in[2];
    const int*  dk = (const int*)d_in[3];
    float* Out = (float*)d_out;

    const int nbh = in_sizes[0] / (SLEN * DH);   // 32
    dim3 grid(nbh * (SLEN / BQ));                // 512 flat
    attn_f16_mfma<<<grid, THREADS, 0, stream>>>(Q, K, V, Out, dk);
}

// Round 5
// 198.517 us; speedup vs baseline: 1.1559x; 1.1559x over previous
//
#include <hip/hip_runtime.h>

// DotProductAttention B=2,H=16,S=2048,D=64 fp32. f16-MFMA flash attention.
// Round 5: round-3 structure (4 waves x 32 q-rows, 256 thr, grid 512) with the
// P buffer re-laid-out: row stride 64 halves, granule swizzle g ^ ((row>>1)&7).
//   writes: g' = 2*(cg^quad)+parity -> 32 banks, 2 lanes/bank same dword (free)
//   reads : aligned ds_read_b128, 8 lanes per 4-bank group, 8 words/bank (floor)

typedef _Float16 half8 __attribute__((ext_vector_type(8)));
typedef float floatx4 __attribute__((ext_vector_type(4)));

constexpr int BQ = 128;
constexpr int BK = 64;
constexpr int DH = 64;
constexpr int SLEN = 2048;
constexpr int NT = SLEN / BK;
constexpr int THREADS = 256;

#define MFMA16(a, b, c) __builtin_amdgcn_mfma_f32_16x16x32_f16(a, b, c, 0, 0, 0)

struct SMem {
    union {
        float qstage[BQ * DH];                  // 32 KB, start only
        struct {
            _Float16 ks[BK * DH];               // 8 KB [key][d],  swz g^(key&7)
            _Float16 vt[DH * BK];               // 8 KB [d][key],  swz g^(d&7)
            _Float16 pw[4][32 * 64];            // 16 KB per-wave P, swz g^((row>>1)&7)
        } s;
    } u;
};

__global__ __launch_bounds__(THREADS, 2)
void attn_f16_mfma(const float* __restrict__ Q, const float* __restrict__ K,
                   const float* __restrict__ V, float* __restrict__ Out,
                   const int* __restrict__ dkp)
{
    __shared__ SMem sm;

    const int tid  = threadIdx.x;
    const int wave = tid >> 6;
    const int lane = tid & 63;
    const int quad = lane >> 4;
    const int n16  = lane & 15;

    // XCD-aware decode: each head's K/V stays in one XCD's L2.
    const int id   = blockIdx.x;
    const int xcd  = id & 7;
    const int slot = id >> 3;
    const int head = xcd * 4 + (slot >> 4);
    const int qt   = slot & 15;

    const float scale2 = rsqrtf((float)(*dkp)) * 1.44269504088896340736f;

    const size_t headoff = (size_t)head * SLEN * DH;

    // ---- stage Q tile (fp32, swizzled), pull scaled f16 A-frags ----
    {
        const float4* Qg = (const float4*)(Q + headoff + (size_t)qt * BQ * DH);
        for (int i = tid; i < BQ * DH / 4; i += THREADS) {
            int row = i >> 4, g = i & 15;
            ((float4*)sm.u.qstage)[row * 16 + (g ^ (row & 15))] = Qg[i];
        }
    }
    __syncthreads();

    half8 qA[2][2];
    #pragma unroll
    for (int rg = 0; rg < 2; rg++) {
        #pragma unroll
        for (int kd = 0; kd < 2; kd++) {
            int row = wave * 32 + rg * 16 + n16;
            int g0 = kd * 8 + quad * 2;
            float4 a = ((const float4*)sm.u.qstage)[row * 16 + (g0 ^ (row & 15))];
            float4 b = ((const float4*)sm.u.qstage)[row * 16 + ((g0 + 1) ^ (row & 15))];
            half8 h;
            h[0] = (_Float16)(a.x * scale2); h[1] = (_Float16)(a.y * scale2);
            h[2] = (_Float16)(a.z * scale2); h[3] = (_Float16)(a.w * scale2);
            h[4] = (_Float16)(b.x * scale2); h[5] = (_Float16)(b.y * scale2);
            h[6] = (_Float16)(b.z * scale2); h[7] = (_Float16)(b.w * scale2);
            qA[rg][kd] = h;
        }
    }
    __syncthreads();   // qstage dead; LDS becomes ks/vt/pw

    const float* Kh = K + headoff;
    const float* Vh = V + headoff;

    // K prefetch: rep t covers row s=(tid+256t)>>3, d-granule g=(tid+256t)&7.
    // V prefetch: rep t covers d=lane, s-granule vg=wave+4t -> 8 strided dwords
    //   (each j: 64 lanes read 256 contiguous bytes).
    float4 kpref[2][2];
    float  vpref[2][8];
    {
        const float4* kp = (const float4*)Kh;
        #pragma unroll
        for (int t = 0; t < 2; t++) {
            int i = tid + 256 * t, s = i >> 3, g = i & 7;
            kpref[t][0] = kp[s * 16 + g * 2];
            kpref[t][1] = kp[s * 16 + g * 2 + 1];
            int vg = (tid >> 6) + 4 * t;
            #pragma unroll
            for (int j = 0; j < 8; j++)
                vpref[t][j] = Vh[(size_t)(vg * 8 + j) * 64 + lane];
        }
    }

    floatx4 oacc[2][4];
    floatx4 lsum[2];
    const floatx4 fz = {0.f, 0.f, 0.f, 0.f};
    #pragma unroll
    for (int rg = 0; rg < 2; rg++) {
        lsum[rg] = fz;
        #pragma unroll
        for (int cg = 0; cg < 4; cg++) oacc[rg][cg] = fz;
    }
    half8 ones;
    #pragma unroll
    for (int j = 0; j < 8; j++) ones[j] = (_Float16)1.0f;

    for (int kt = 0; kt < NT; ++kt) {
        __syncthreads();   // prev iteration's ks/vt reads done

        // ---- stage K: one b128 per rep, conflict-free (g^(s&7)) ----
        #pragma unroll
        for (int t = 0; t < 2; t++) {
            int i = tid + 256 * t, s = i >> 3, g = i & 7;
            float4 a = kpref[t][0], b = kpref[t][1];
            half8 h;
            h[0] = (_Float16)a.x; h[1] = (_Float16)a.y;
            h[2] = (_Float16)a.z; h[3] = (_Float16)a.w;
            h[4] = (_Float16)b.x; h[5] = (_Float16)b.y;
            h[6] = (_Float16)b.z; h[7] = (_Float16)b.w;
            *(half8*)&sm.u.s.ks[s * 64 + ((g ^ (s & 7)) << 3)] = h;
        }
        // ---- stage V transposed: one b128 per rep, conflict-free (g^(d&7)) ----
        #pragma unroll
        for (int t = 0; t < 2; t++) {
            int vg = (tid >> 6) + 4 * t;
            half8 h;
            #pragma unroll
            for (int j = 0; j < 8; j++) h[j] = (_Float16)vpref[t][j];
            *(half8*)&sm.u.s.vt[lane * 64 + ((vg ^ (lane & 7)) << 3)] = h;
        }
        // issue next tile's global loads (overlap with compute)
        if (kt + 1 < NT) {
            const float4* kp = (const float4*)(Kh + (size_t)(kt + 1) * BK * DH);
            const float*  vp = Vh + (size_t)(kt + 1) * BK * DH;
            #pragma unroll
            for (int t = 0; t < 2; t++) {
                int i = tid + 256 * t, s = i >> 3, g = i & 7;
                kpref[t][0] = kp[s * 16 + g * 2];
                kpref[t][1] = kp[s * 16 + g * 2 + 1];
                int vg = (tid >> 6) + 4 * t;
                #pragma unroll
                for (int j = 0; j < 8; j++)
                    vpref[t][j] = vp[(size_t)(vg * 8 + j) * 64 + lane];
            }
        }
        __syncthreads();   // ks/vt visible

        // ---- K B-frags; S = Q K^T ----
        half8 kB[2][4];
        #pragma unroll
        for (int kd = 0; kd < 2; kd++)
            #pragma unroll
            for (int cg = 0; cg < 4; cg++) {
                int key = cg * 16 + n16;
                int g = (kd * 4 + quad) ^ (key & 7);
                kB[kd][cg] = *(const half8*)&sm.u.s.ks[key * 64 + (g << 3)];
            }
        floatx4 sC[2][4];
        #pragma unroll
        for (int rg = 0; rg < 2; rg++)
            #pragma unroll
            for (int cg = 0; cg < 4; cg++) {
                floatx4 c = MFMA16(qA[rg][0], kB[0][cg], fz);
                sC[rg][cg] = MFMA16(qA[rg][1], kB[1][cg], c);
            }

        // ---- P = exp2(S) -> per-wave LDS, swz g^((row>>1)&7) ----
        // write banks: g' = 2*(cg^quad)+parity -> all 32 banks, 2 lanes/dword.
        _Float16* P = sm.u.s.pw[wave];
        #pragma unroll
        for (int rg = 0; rg < 2; rg++)
            #pragma unroll
            for (int cg = 0; cg < 4; cg++)
                #pragma unroll
                for (int r = 0; r < 4; r++) {
                    int row = rg * 16 + quad * 4 + r;
                    int col = cg * 16 + n16;
                    int s = (row >> 1) & 7;
                    P[row * 64 + ((((col >> 3) ^ s) << 3) | (col & 7))] =
                        (_Float16)exp2f(sC[rg][cg][r]);
                }

        // ---- P A-frags (intra-wave round trip; aligned b128, floor-optimal) ----
        half8 pA[2][2];
        #pragma unroll
        for (int rg = 0; rg < 2; rg++)
            #pragma unroll
            for (int kd = 0; kd < 2; kd++) {
                int row = rg * 16 + n16;
                int g = (kd * 4 + quad) ^ ((row >> 1) & 7);
                pA[rg][kd] = *(const half8*)&P[row * 64 + (g << 3)];
            }
        // ---- V B-frags ----
        half8 vB[2][4];
        #pragma unroll
        for (int kd = 0; kd < 2; kd++)
            #pragma unroll
            for (int cg = 0; cg < 4; cg++) {
                int d = cg * 16 + n16;
                int g = (kd * 4 + quad) ^ (d & 7);
                vB[kd][cg] = *(const half8*)&sm.u.s.vt[d * 64 + (g << 3)];
            }

        // ---- row sums (ones-MFMA) and O += P V ----
        #pragma unroll
        for (int rg = 0; rg < 2; rg++) {
            lsum[rg] = MFMA16(pA[rg][0], ones, lsum[rg]);
            lsum[rg] = MFMA16(pA[rg][1], ones, lsum[rg]);
        }
        #pragma unroll
        for (int rg = 0; rg < 2; rg++)
            #pragma unroll
            for (int cg = 0; cg < 4; cg++) {
                oacc[rg][cg] = MFMA16(pA[rg][0], vB[0][cg], oacc[rg][cg]);
                oacc[rg][cg] = MFMA16(pA[rg][1], vB[1][cg], oacc[rg][cg]);
            }
    }

    // ---- epilogue: O / l, fp32 store ----
    float* Og = Out + headoff + (size_t)qt * BQ * DH;
    #pragma unroll
    for (int rg = 0; rg < 2; rg++)
        #pragma unroll
        for (int r = 0; r < 4; r++) {
            float inv = 1.0f / lsum[rg][r];
            int row = wave * 32 + rg * 16 + quad * 4 + r;
            #pragma unroll
            for (int cg = 0; cg < 4; cg++)
                Og[row * 64 + cg * 16 + n16] = oacc[rg][cg][r] * inv;
        }
}

extern "C" void kernel_launch(void* const* d_in, const int* in_sizes, int n_in,
                              void* d_out, int out_size, void* d_ws, size_t ws_size,
                              hipStream_t stream) {
    const float* Q = (const float*)d_in[0];
    const float* K = (const float*)d_in[1];
    const float* V = (const float*)d_in[2];
    const int*  dk = (const int*)d_in[3];
    float* Out = (float*)d_out;

    const int nbh = in_sizes[0] / (SLEN * DH);   // 32
    dim3 grid(nbh * (SLEN / BQ));                // 512 flat
    attn_f16_mfma<<<grid, THREADS, 0, stream>>>(Q, K, V, Out, dk);
}

// Round 6
// 187.711 us; speedup vs baseline: 1.2225x; 1.0576x over previous
//
#include <hip/hip_runtime.h>

// DotProductAttention B=2,H=16,S=2048,D=64 fp32. f16-MFMA flash attention.
// Round 6: operand-swapped GEMMs. C1 = K*Q^T puts keys in the reg-dim so
// P^T stages with 8 b64 writes + 4 b128 reads (was 32 scalar + 4 b128).
// GEMM2 computes O^T = V^T * P^T; epilogue transposes O via LDS once.

typedef _Float16 half8 __attribute__((ext_vector_type(8)));
typedef _Float16 half4 __attribute__((ext_vector_type(4)));
typedef float floatx4 __attribute__((ext_vector_type(4)));

constexpr int BQ = 128;
constexpr int BK = 64;
constexpr int DH = 64;
constexpr int SLEN = 2048;
constexpr int NT = SLEN / BK;
constexpr int THREADS = 256;
constexpr int PSTR = 72;   // halves per P^T row (144 B): b128 reads conflict-free

#define MFMA16(a, b, c) __builtin_amdgcn_mfma_f32_16x16x32_f16(a, b, c, 0, 0, 0)

struct SMem {
    union {
        float qstage[BQ * DH];                  // 32 KB, start only
        struct {
            _Float16 ks[BK * DH];               // 8 KB [key][d], swz g^(key&7)
            _Float16 vt[DH * BK];               // 8 KB [d][key], swz g^(d&7)
            _Float16 pt[4][32 * PSTR];          // 18 KB per-wave P^T [q_local][key]
        } s;
    } u;
};

__global__ __launch_bounds__(THREADS, 2)
void attn_f16_mfma(const float* __restrict__ Q, const float* __restrict__ K,
                   const float* __restrict__ V, float* __restrict__ Out,
                   const int* __restrict__ dkp)
{
    __shared__ SMem sm;

    const int tid  = threadIdx.x;
    const int wave = tid >> 6;
    const int lane = tid & 63;
    const int quad = lane >> 4;
    const int n16  = lane & 15;

    // XCD-aware decode: each head's K/V stays in one XCD's L2.
    const int id   = blockIdx.x;
    const int xcd  = id & 7;
    const int slot = id >> 3;
    const int head = xcd * 4 + (slot >> 4);
    const int qt   = slot & 15;

    const float scale2 = rsqrtf((float)(*dkp)) * 1.44269504088896340736f;

    const size_t headoff = (size_t)head * SLEN * DH;

    // ---- stage Q tile (fp32, swizzled), pull scaled f16 B-frags ----
    {
        const float4* Qg = (const float4*)(Q + headoff + (size_t)qt * BQ * DH);
        for (int i = tid; i < BQ * DH / 4; i += THREADS) {
            int row = i >> 4, g = i & 15;
            ((float4*)sm.u.qstage)[row * 16 + (g ^ (row & 15))] = Qg[i];
        }
    }
    __syncthreads();

    half8 qB[2][2];   // [rg][kd]: B-frag, n = q = rg*16+n16, k = d = kd*32+quad*8+j
    #pragma unroll
    for (int rg = 0; rg < 2; rg++) {
        #pragma unroll
        for (int kd = 0; kd < 2; kd++) {
            int row = wave * 32 + rg * 16 + n16;
            int g0 = kd * 8 + quad * 2;
            float4 a = ((const float4*)sm.u.qstage)[row * 16 + (g0 ^ (row & 15))];
            float4 b = ((const float4*)sm.u.qstage)[row * 16 + ((g0 + 1) ^ (row & 15))];
            half8 h;
            h[0] = (_Float16)(a.x * scale2); h[1] = (_Float16)(a.y * scale2);
            h[2] = (_Float16)(a.z * scale2); h[3] = (_Float16)(a.w * scale2);
            h[4] = (_Float16)(b.x * scale2); h[5] = (_Float16)(b.y * scale2);
            h[6] = (_Float16)(b.z * scale2); h[7] = (_Float16)(b.w * scale2);
            qB[rg][kd] = h;
        }
    }
    __syncthreads();   // qstage dead; LDS becomes ks/vt/pt

    const float* Kh = K + headoff;
    const float* Vh = V + headoff;

    float4 kpref[2][2];
    float  vpref[2][8];
    {
        const float4* kp = (const float4*)Kh;
        #pragma unroll
        for (int t = 0; t < 2; t++) {
            int i = tid + 256 * t, s = i >> 3, g = i & 7;
            kpref[t][0] = kp[s * 16 + g * 2];
            kpref[t][1] = kp[s * 16 + g * 2 + 1];
            int vg = (tid >> 6) + 4 * t;
            #pragma unroll
            for (int j = 0; j < 8; j++)
                vpref[t][j] = Vh[(size_t)(vg * 8 + j) * 64 + lane];
        }
    }

    floatx4 oacc[2][4];      // [rg][dg]: O^T tile, row d = dg*16+quad*4+r, col q
    floatx4 lsum[2];
    const floatx4 fz = {0.f, 0.f, 0.f, 0.f};
    #pragma unroll
    for (int rg = 0; rg < 2; rg++) {
        lsum[rg] = fz;
        #pragma unroll
        for (int dg = 0; dg < 4; dg++) oacc[rg][dg] = fz;
    }
    half8 ones;
    #pragma unroll
    for (int j = 0; j < 8; j++) ones[j] = (_Float16)1.0f;

    for (int kt = 0; kt < NT; ++kt) {
        __syncthreads();

        // ---- stage K: b128, conflict-free (g^(s&7)) ----
        #pragma unroll
        for (int t = 0; t < 2; t++) {
            int i = tid + 256 * t, s = i >> 3, g = i & 7;
            float4 a = kpref[t][0], b = kpref[t][1];
            half8 h;
            h[0] = (_Float16)a.x; h[1] = (_Float16)a.y;
            h[2] = (_Float16)a.z; h[3] = (_Float16)a.w;
            h[4] = (_Float16)b.x; h[5] = (_Float16)b.y;
            h[6] = (_Float16)b.z; h[7] = (_Float16)b.w;
            *(half8*)&sm.u.s.ks[s * 64 + ((g ^ (s & 7)) << 3)] = h;
        }
        // ---- stage V^T: b128, conflict-free (g^(d&7)) ----
        #pragma unroll
        for (int t = 0; t < 2; t++) {
            int vg = (tid >> 6) + 4 * t;
            half8 h;
            #pragma unroll
            for (int j = 0; j < 8; j++) h[j] = (_Float16)vpref[t][j];
            *(half8*)&sm.u.s.vt[lane * 64 + ((vg ^ (lane & 7)) << 3)] = h;
        }
        if (kt + 1 < NT) {
            const float4* kp = (const float4*)(Kh + (size_t)(kt + 1) * BK * DH);
            const float*  vp = Vh + (size_t)(kt + 1) * BK * DH;
            #pragma unroll
            for (int t = 0; t < 2; t++) {
                int i = tid + 256 * t, s = i >> 3, g = i & 7;
                kpref[t][0] = kp[s * 16 + g * 2];
                kpref[t][1] = kp[s * 16 + g * 2 + 1];
                int vg = (tid >> 6) + 4 * t;
                #pragma unroll
                for (int j = 0; j < 8; j++)
                    vpref[t][j] = vp[(size_t)(vg * 8 + j) * 64 + lane];
            }
        }
        __syncthreads();

        // ---- K A-frags: m = key = c*16+n16, k = d = kd*32+quad*8+j ----
        half8 kA[2][4];
        #pragma unroll
        for (int kd = 0; kd < 2; kd++)
            #pragma unroll
            for (int c = 0; c < 4; c++) {
                int key = c * 16 + n16;
                int g = (kd * 4 + quad) ^ (key & 7);
                kA[kd][c] = *(const half8*)&sm.u.s.ks[key * 64 + (g << 3)];
            }
        // ---- GEMM1: C1 = K * Q^T -> C1[key][q], key in reg-dim ----
        floatx4 sC[2][4];   // [rg][c]: key = c*16 + quad*4 + r, q = rg*16+n16
        #pragma unroll
        for (int rg = 0; rg < 2; rg++)
            #pragma unroll
            for (int c = 0; c < 4; c++) {
                floatx4 acc = MFMA16(kA[0][c], qB[rg][0], fz);
                sC[rg][c] = MFMA16(kA[1][c], qB[rg][1], acc);
            }

        // ---- P^T = exp2(C1) -> per-wave LDS, vectorized b64 writes ----
        _Float16* Pw = sm.u.s.pt[wave];
        #pragma unroll
        for (int rg = 0; rg < 2; rg++)
            #pragma unroll
            for (int c = 0; c < 4; c++) {
                half4 h;
                #pragma unroll
                for (int r = 0; r < 4; r++) h[r] = (_Float16)exp2f(sC[rg][c][r]);
                *(half4*)&Pw[(rg * 16 + n16) * PSTR + c * 16 + quad * 4] = h;
            }

        // ---- P^T B-frags (intra-wave; aligned b128, conflict-free) ----
        half8 pB[2][2];   // [rg][kd2]: k = key = kd2*32+quad*8+j, n = q
        #pragma unroll
        for (int rg = 0; rg < 2; rg++)
            #pragma unroll
            for (int kd2 = 0; kd2 < 2; kd2++)
                pB[rg][kd2] = *(const half8*)&Pw[(rg * 16 + n16) * PSTR + kd2 * 32 + quad * 8];

        // ---- V^T A-frags: m = d = dg*16+n16, k = key ----
        half8 vA[2][4];
        #pragma unroll
        for (int kd2 = 0; kd2 < 2; kd2++)
            #pragma unroll
            for (int dg = 0; dg < 4; dg++) {
                int d = dg * 16 + n16;
                int g = (kd2 * 4 + quad) ^ (d & 7);
                vA[kd2][dg] = *(const half8*)&sm.u.s.vt[d * 64 + (g << 3)];
            }

        // ---- lsum (ones-A MFMA) and O^T += V^T * P^T ----
        #pragma unroll
        for (int rg = 0; rg < 2; rg++) {
            lsum[rg] = MFMA16(ones, pB[rg][0], lsum[rg]);
            lsum[rg] = MFMA16(ones, pB[rg][1], lsum[rg]);
        }
        #pragma unroll
        for (int rg = 0; rg < 2; rg++)
            #pragma unroll
            for (int dg = 0; dg < 4; dg++) {
                oacc[rg][dg] = MFMA16(vA[0][dg], pB[rg][0], oacc[rg][dg]);
                oacc[rg][dg] = MFMA16(vA[1][dg], pB[rg][1], oacc[rg][dg]);
            }
    }

    // ---- epilogue: normalize in-lane (q is in lanes), transpose via LDS ----
    float* fb = (float*)sm.u.s.pt[wave];     // per-wave scratch, stride 68 floats
    float* Og = Out + headoff + (size_t)qt * BQ * DH;
    const int qr = lane >> 2;    // 0..15
    const int dq = lane & 3;     // d-quarter
    #pragma unroll
    for (int rg = 0; rg < 2; rg++) {
        float inv = 1.0f / lsum[rg][0];
        #pragma unroll
        for (int dg = 0; dg < 4; dg++)
            #pragma unroll
            for (int r = 0; r < 4; r++)
                fb[n16 * 68 + dg * 16 + quad * 4 + r] = oacc[rg][dg][r] * inv;
        // same-wave DS ordering guarantees RAW here (same property the P
        // round-trip relies on).
        #pragma unroll
        for (int t = 0; t < 4; t++) {
            float4 v = *(const float4*)&fb[qr * 68 + dq * 16 + t * 4];
            int row = wave * 32 + rg * 16 + qr;
            *(float4*)&Og[row * 64 + dq * 16 + t * 4] = v;
        }
    }
}

extern "C" void kernel_launch(void* const* d_in, const int* in_sizes, int n_in,
                              void* d_out, int out_size, void* d_ws, size_t ws_size,
                              hipStream_t stream) {
    const float* Q = (const float*)d_in[0];
    const float* K = (const float*)d_in[1];
    const float* V = (const float*)d_in[2];
    const int*  dk = (const int*)d_in[3];
    float* Out = (float*)d_out;

    const int nbh = in_sizes[0] / (SLEN * DH);   // 32
    dim3 grid(nbh * (SLEN / BQ));                // 512 flat
    attn_f16_mfma<<<grid, THREADS, 0, stream>>>(Q, K, V, Out, dk);
}

// Round 7
// 186.923 us; speedup vs baseline: 1.2276x; 1.0042x over previous
//
#include <hip/hip_runtime.h>

// DotProductAttention B=2,H=16,S=2048,D=64 fp32. f16-MFMA flash attention.
// Round 7: 2x2 wave tiling (wm = key/d half, wn = q half; each wave 64 q-rows)
// cuts kA+vA frag reads in half (16 b128 total, was 20); double-buffered K/V
// staging overlapped with GEMM2 between restructured barriers.

typedef _Float16 half8 __attribute__((ext_vector_type(8)));
typedef _Float16 half4 __attribute__((ext_vector_type(4)));
typedef float floatx4 __attribute__((ext_vector_type(4)));

constexpr int BQ = 128;
constexpr int BK = 64;
constexpr int DH = 64;
constexpr int SLEN = 2048;
constexpr int NT = SLEN / BK;
constexpr int THREADS = 256;
constexpr int PSTR = 72;   // halves per P^T row (144 B)

#define MFMA16(a, b, c) __builtin_amdgcn_mfma_f32_16x16x32_f16(a, b, c, 0, 0, 0)

struct SMem {
    union {
        float qstage[BQ * DH];                  // 32 KB, start only
        struct {
            _Float16 ks[2][BK * DH];            // 16 KB dbuf [key][d], swz g^(key&7)
            _Float16 vt[2][DH * BK];            // 16 KB dbuf [d][key], swz g^(d&7)
            _Float16 pt[BQ * PSTR];             // 18 KB block-shared P^T [q][key]
        } s;
    } u;
};

__global__ __launch_bounds__(THREADS, 2)
void attn_f16_mfma(const float* __restrict__ Q, const float* __restrict__ K,
                   const float* __restrict__ V, float* __restrict__ Out,
                   const int* __restrict__ dkp)
{
    __shared__ SMem sm;

    const int tid  = threadIdx.x;
    const int wave = tid >> 6;
    const int lane = tid & 63;
    const int quad = lane >> 4;
    const int n16  = lane & 15;
    const int wm   = wave & 1;     // key/d half: [wm*32, wm*32+32)
    const int wn   = wave >> 1;    // q half:     [wn*64, wn*64+64)

    const int id   = blockIdx.x;
    const int xcd  = id & 7;
    const int slot = id >> 3;
    const int head = xcd * 4 + (slot >> 4);
    const int qt   = slot & 15;

    const float scale2 = rsqrtf((float)(*dkp)) * 1.44269504088896340736f;
    const size_t headoff = (size_t)head * SLEN * DH;

    // ---- stage Q tile (fp32, swizzled), pull scaled f16 B-frags ----
    {
        const float4* Qg = (const float4*)(Q + headoff + (size_t)qt * BQ * DH);
        for (int i = tid; i < BQ * DH / 4; i += THREADS) {
            int row = i >> 4, g = i & 15;
            ((float4*)sm.u.qstage)[row * 16 + (g ^ (row & 15))] = Qg[i];
        }
    }
    __syncthreads();

    half8 qB[4][2];   // [rg][kd]: n = q = wn*64+rg*16+n16, k = d = kd*32+quad*8+j
    #pragma unroll
    for (int rg = 0; rg < 4; rg++) {
        #pragma unroll
        for (int kd = 0; kd < 2; kd++) {
            int row = wn * 64 + rg * 16 + n16;
            int g0 = kd * 8 + quad * 2;
            float4 a = ((const float4*)sm.u.qstage)[row * 16 + (g0 ^ (row & 15))];
            float4 b = ((const float4*)sm.u.qstage)[row * 16 + ((g0 + 1) ^ (row & 15))];
            half8 h;
            h[0] = (_Float16)(a.x * scale2); h[1] = (_Float16)(a.y * scale2);
            h[2] = (_Float16)(a.z * scale2); h[3] = (_Float16)(a.w * scale2);
            h[4] = (_Float16)(b.x * scale2); h[5] = (_Float16)(b.y * scale2);
            h[6] = (_Float16)(b.z * scale2); h[7] = (_Float16)(b.w * scale2);
            qB[rg][kd] = h;
        }
    }
    __syncthreads();   // qstage dead; union becomes ks/vt/pt

    const float* Kh = K + headoff;
    const float* Vh = V + headoff;

    float4 kpref[2][2];
    float  vpref[2][8];

    auto loadKV = [&](int kt) {
        const float4* kp = (const float4*)(Kh + (size_t)kt * BK * DH);
        const float*  vp = Vh + (size_t)kt * BK * DH;
        #pragma unroll
        for (int t = 0; t < 2; t++) {
            int i = tid + 256 * t, s = i >> 3, g = i & 7;
            kpref[t][0] = kp[s * 16 + g * 2];
            kpref[t][1] = kp[s * 16 + g * 2 + 1];
            int vg = wave + 4 * t;
            #pragma unroll
            for (int j = 0; j < 8; j++)
                vpref[t][j] = vp[(size_t)(vg * 8 + j) * 64 + lane];
        }
    };
    auto stageKV = [&](int b) {
        #pragma unroll
        for (int t = 0; t < 2; t++) {
            int i = tid + 256 * t, s = i >> 3, g = i & 7;
            float4 a = kpref[t][0], bb = kpref[t][1];
            half8 h;
            h[0] = (_Float16)a.x;  h[1] = (_Float16)a.y;
            h[2] = (_Float16)a.z;  h[3] = (_Float16)a.w;
            h[4] = (_Float16)bb.x; h[5] = (_Float16)bb.y;
            h[6] = (_Float16)bb.z; h[7] = (_Float16)bb.w;
            *(half8*)&sm.u.s.ks[b][s * 64 + ((g ^ (s & 7)) << 3)] = h;
            int vg = wave + 4 * t;
            half8 hv;
            #pragma unroll
            for (int j = 0; j < 8; j++) hv[j] = (_Float16)vpref[t][j];
            *(half8*)&sm.u.s.vt[b][lane * 64 + ((vg ^ (lane & 7)) << 3)] = hv;
        }
    };

    // ---- pre-loop pipeline: load+stage tile 0, load tile 1 ----
    loadKV(0);
    stageKV(0);
    if (NT > 1) loadKV(1);

    floatx4 oacc[4][2];   // [rg][c2]: d = wm*32+c2*16+quad*4+r, q = wn*64+rg*16+n16
    floatx4 lsum[4];
    const floatx4 fz = {0.f, 0.f, 0.f, 0.f};
    #pragma unroll
    for (int rg = 0; rg < 4; rg++) {
        lsum[rg] = fz;
        #pragma unroll
        for (int c2 = 0; c2 < 2; c2++) oacc[rg][c2] = fz;
    }
    half8 ones;
    #pragma unroll
    for (int j = 0; j < 8; j++) ones[j] = (_Float16)1.0f;

    __syncthreads();   // tile-0 staging visible

    for (int kt = 0; kt < NT; ++kt) {
        const int rb = kt & 1;

        // ---- (B) GEMM1: C1 = K * Q^T over this wave's key half ----
        half8 kA[2][2];   // [kd][c]: m = key = wm*32+c*16+n16, k = d
        #pragma unroll
        for (int kd = 0; kd < 2; kd++)
            #pragma unroll
            for (int c = 0; c < 2; c++) {
                int key = wm * 32 + c * 16 + n16;
                int g = (kd * 4 + quad) ^ (n16 & 7);
                kA[kd][c] = *(const half8*)&sm.u.s.ks[rb][key * 64 + (g << 3)];
            }
        floatx4 sC[4][2];   // [rg][c]: key = wm*32+c*16+quad*4+r, q = wn*64+rg*16+n16
        #pragma unroll
        for (int rg = 0; rg < 4; rg++)
            #pragma unroll
            for (int c = 0; c < 2; c++) {
                floatx4 acc = MFMA16(kA[0][c], qB[rg][0], fz);
                sC[rg][c] = MFMA16(kA[1][c], qB[rg][1], acc);
            }
        // ---- P^T = exp2(C1) -> shared pt, b64 writes (bank floor) ----
        #pragma unroll
        for (int rg = 0; rg < 4; rg++)
            #pragma unroll
            for (int c = 0; c < 2; c++) {
                half4 h;
                #pragma unroll
                for (int r = 0; r < 4; r++) h[r] = (_Float16)exp2f(sC[rg][c][r]);
                int q = wn * 64 + rg * 16 + n16;
                *(half4*)&sm.u.s.pt[q * PSTR + wm * 32 + c * 16 + quad * 4] = h;
            }
        __syncthreads();   // sync1: P^T visible across wm halves

        // ---- (C) GEMM2: O^T += V^T * P^T (this wave's d half, all keys) ----
        half8 pB[4][2];   // [rg][kd2]: k = key = kd2*32+quad*8+j, n = q
        #pragma unroll
        for (int rg = 0; rg < 4; rg++)
            #pragma unroll
            for (int kd2 = 0; kd2 < 2; kd2++)
                pB[rg][kd2] = *(const half8*)
                    &sm.u.s.pt[(wn * 64 + rg * 16 + n16) * PSTR + kd2 * 32 + quad * 8];
        half8 vA[2][2];   // [kd2][c2]: m = d = wm*32+c2*16+n16, k = key
        #pragma unroll
        for (int kd2 = 0; kd2 < 2; kd2++)
            #pragma unroll
            for (int c2 = 0; c2 < 2; c2++) {
                int d = wm * 32 + c2 * 16 + n16;
                int g = (kd2 * 4 + quad) ^ (n16 & 7);
                vA[kd2][c2] = *(const half8*)&sm.u.s.vt[rb][d * 64 + (g << 3)];
            }
        #pragma unroll
        for (int rg = 0; rg < 4; rg++) {
            lsum[rg] = MFMA16(ones, pB[rg][0], lsum[rg]);
            lsum[rg] = MFMA16(ones, pB[rg][1], lsum[rg]);
        }
        #pragma unroll
        for (int rg = 0; rg < 4; rg++)
            #pragma unroll
            for (int c2 = 0; c2 < 2; c2++) {
                oacc[rg][c2] = MFMA16(vA[0][c2], pB[rg][0], oacc[rg][c2]);
                oacc[rg][c2] = MFMA16(vA[1][c2], pB[rg][1], oacc[rg][c2]);
            }

        // ---- overlap: stage kt+1 into buf^1, issue loads for kt+2 ----
        if (kt + 1 < NT) stageKV(1 - rb);
        if (kt + 2 < NT) loadKV(kt + 2);
        __syncthreads();   // sync2: staged buf^1 visible; pt free for rewrite
    }

    // ---- epilogue: normalize (q in lanes), transpose via per-wave scratch ----
    float* scratch = (float*)sm.u.s.pt + wave * 576;   // 16 rows x 36 f32
    float* Og = Out + headoff + (size_t)qt * BQ * DH;
    const int qr = lane >> 2;
    const int dh = lane & 3;
    #pragma unroll
    for (int rg = 0; rg < 4; rg++) {
        float inv = 1.0f / lsum[rg][0];
        #pragma unroll
        for (int c2 = 0; c2 < 2; c2++) {
            floatx4 v = oacc[rg][c2];
            float4 w = make_float4(v[0] * inv, v[1] * inv, v[2] * inv, v[3] * inv);
            *(float4*)&scratch[n16 * 36 + c2 * 16 + quad * 4] = w;
        }
        // in-wave DS ordering (same property as prior rounds' P round-trip)
        float4 r0 = *(const float4*)&scratch[qr * 36 + dh * 8];
        float4 r1 = *(const float4*)&scratch[qr * 36 + dh * 8 + 4];
        int row = wn * 64 + rg * 16 + qr;
        *(float4*)&Og[row * 64 + wm * 32 + dh * 8] = r0;
        *(float4*)&Og[row * 64 + wm * 32 + dh * 8 + 4] = r1;
    }
}

extern "C" void kernel_launch(void* const* d_in, const int* in_sizes, int n_in,
                              void* d_out, int out_size, void* d_ws, size_t ws_size,
                              hipStream_t stream) {
    const float* Q = (const float*)d_in[0];
    const float* K = (const float*)d_in[1];
    const float* V = (const float*)d_in[2];
    const int*  dk = (const int*)d_in[3];
    float* Out = (float*)d_out;

    const int nbh = in_sizes[0] / (SLEN * DH);   // 32
    dim3 grid(nbh * (SLEN / BQ));                // 512 flat
    attn_f16_mfma<<<grid, THREADS, 0, stream>>>(Q, K, V, Out, dk);
}

// Round 8
// 163.042 us; speedup vs baseline: 1.4074x; 1.1465x over previous
//
#include <hip/hip_runtime.h>

// DotProductAttention B=2,H=16,S=2048,D=64 fp32. f16-MFMA flash attention.
// Round 8: K/V leave the LDS pipe. Prepass converts K->f16 and V->V^T f16 in
// d_ws; main kernel loads all K/V fragments directly from global (L2-hot
// dwordx4). LDS holds only the P^T round-trip (18 KB) -> 12 waves/CU.

typedef _Float16 half8 __attribute__((ext_vector_type(8)));
typedef _Float16 half4 __attribute__((ext_vector_type(4)));
typedef float floatx4 __attribute__((ext_vector_type(4)));

constexpr int BQ = 128;
constexpr int BK = 64;
constexpr int DH = 64;
constexpr int SLEN = 2048;
constexpr int NT = SLEN / BK;
constexpr int THREADS = 256;
constexpr int PSTR = 72;   // halves per P^T row (144 B)

#define MFMA16(a, b, c) __builtin_amdgcn_mfma_f32_16x16x32_f16(a, b, c, 0, 0, 0)

// ---- prepass 1: K fp32 -> f16, same [head][key][d] layout ----
__global__ __launch_bounds__(256)
void cvt_k_kernel(const float* __restrict__ K, _Float16* __restrict__ Kh, int n8)
{
    int i = blockIdx.x * 256 + threadIdx.x;
    if (i < n8) {
        const float4* src = (const float4*)K;
        float4 a = src[2 * i], b = src[2 * i + 1];
        half8 h;
        h[0] = (_Float16)a.x; h[1] = (_Float16)a.y;
        h[2] = (_Float16)a.z; h[3] = (_Float16)a.w;
        h[4] = (_Float16)b.x; h[5] = (_Float16)b.y;
        h[6] = (_Float16)b.z; h[7] = (_Float16)b.w;
        ((half8*)Kh)[i] = h;
    }
}

// ---- prepass 2: V fp32 [head][key][d] -> V^T f16 [head][d][key] ----
__global__ __launch_bounds__(256)
void tr_v_kernel(const float* __restrict__ V, _Float16* __restrict__ Vt)
{
    __shared__ _Float16 t[64 * 72];
    const int tid  = threadIdx.x;
    const int tile = blockIdx.x & 31;
    const int head = blockIdx.x >> 5;
    const float4* src = (const float4*)(V + ((size_t)head * SLEN + tile * 64) * DH);
    #pragma unroll
    for (int r = 0; r < 4; r++) {
        int i = tid + 256 * r, row = i >> 4, g = i & 15;
        float4 a = src[row * 16 + g];
        half4 h;
        h[0] = (_Float16)a.x; h[1] = (_Float16)a.y;
        h[2] = (_Float16)a.z; h[3] = (_Float16)a.w;
        *(half4*)&t[row * 72 + g * 4] = h;
    }
    __syncthreads();
    _Float16* dst = Vt + (size_t)head * DH * SLEN + tile * 64;
    #pragma unroll
    for (int r = 0; r < 2; r++) {
        int i = tid + 256 * r, d = i >> 3, g = i & 7;
        half8 h;
        #pragma unroll
        for (int j = 0; j < 8; j++) h[j] = t[(g * 8 + j) * 72 + d];
        *(half8*)&dst[(size_t)d * SLEN + g * 8] = h;
    }
}

// ---- main flash-attention kernel ----
__global__ __launch_bounds__(THREADS, 3)
void attn_f16_mfma(const float* __restrict__ Q, const _Float16* __restrict__ Kh,
                   const _Float16* __restrict__ Vt, float* __restrict__ Out,
                   const int* __restrict__ dkp)
{
    __shared__ _Float16 pt[BQ * PSTR];   // 18 KB: P^T [q_local][key] only

    const int tid  = threadIdx.x;
    const int wave = tid >> 6;
    const int lane = tid & 63;
    const int quad = lane >> 4;
    const int n16  = lane & 15;
    const int wm   = wave & 1;     // key/d half
    const int wn   = wave >> 1;    // q half

    const int id   = blockIdx.x;
    const int xcd  = id & 7;
    const int slot = id >> 3;
    const int head = xcd * 4 + (slot >> 4);
    const int qt   = slot & 15;

    const float scale2 = rsqrtf((float)(*dkp)) * 1.44269504088896340736f;
    const size_t headoff = (size_t)head * SLEN * DH;

    // ---- Q B-frags direct from global (fp32, scaled, cvt to f16) ----
    half8 qB[4][2];   // [rg][kd]: n = q = wn*64+rg*16+n16, k = d = kd*32+quad*8+j
    {
        const float4* Qg = (const float4*)(Q + headoff + (size_t)qt * BQ * DH);
        #pragma unroll
        for (int rg = 0; rg < 4; rg++)
            #pragma unroll
            for (int kd = 0; kd < 2; kd++) {
                int row = wn * 64 + rg * 16 + n16;
                float4 a = Qg[row * 16 + kd * 8 + quad * 2];
                float4 b = Qg[row * 16 + kd * 8 + quad * 2 + 1];
                half8 h;
                h[0] = (_Float16)(a.x * scale2); h[1] = (_Float16)(a.y * scale2);
                h[2] = (_Float16)(a.z * scale2); h[3] = (_Float16)(a.w * scale2);
                h[4] = (_Float16)(b.x * scale2); h[5] = (_Float16)(b.y * scale2);
                h[6] = (_Float16)(b.z * scale2); h[7] = (_Float16)(b.w * scale2);
                qB[rg][kd] = h;
            }
    }

    const _Float16* Khh = Kh + headoff;             // [key][d] f16
    const _Float16* Vth = Vt + (size_t)head * DH * SLEN;   // [d][key] f16

    // kA frag loader: m = key = kb+wm*32+c*16+n16, k = d = kd*32+quad*8+j
    auto loadK = [&](int kt, half8 kA[2][2]) {
        int kb = kt * BK;
        #pragma unroll
        for (int kd = 0; kd < 2; kd++)
            #pragma unroll
            for (int c = 0; c < 2; c++)
                kA[kd][c] = *(const half8*)
                    &Khh[(size_t)(kb + wm * 32 + c * 16 + n16) * 64 + kd * 32 + quad * 8];
    };
    // vA frag loader: m = d = wm*32+c2*16+n16, k = key = kb+kd2*32+quad*8+j
    auto loadV = [&](int kt, half8 vA[2][2]) {
        int kb = kt * BK;
        #pragma unroll
        for (int kd2 = 0; kd2 < 2; kd2++)
            #pragma unroll
            for (int c2 = 0; c2 < 2; c2++)
                vA[kd2][c2] = *(const half8*)
                    &Vth[(size_t)(wm * 32 + c2 * 16 + n16) * SLEN + kb + kd2 * 32 + quad * 8];
    };

    floatx4 oacc[4][2];   // [rg][c2]: d = wm*32+c2*16+quad*4+r, q = wn*64+rg*16+n16
    floatx4 lsum[4];
    const floatx4 fz = {0.f, 0.f, 0.f, 0.f};
    #pragma unroll
    for (int rg = 0; rg < 4; rg++) {
        lsum[rg] = fz;
        #pragma unroll
        for (int c2 = 0; c2 < 2; c2++) oacc[rg][c2] = fz;
    }
    half8 ones;
    #pragma unroll
    for (int j = 0; j < 8; j++) ones[j] = (_Float16)1.0f;

    half8 kA[2][2], kAn[2][2], vA[2][2];
    loadK(0, kA);

    for (int kt = 0; kt < NT; ++kt) {
        // issue vA loads now; consumed after sync1 (long overlap window)
        loadV(kt, vA);

        // ---- GEMM1: C1 = K * Q^T (this wave's 32-key half) ----
        floatx4 sC[4][2];   // [rg][c]: key = wm*32+c*16+quad*4+r, q = wn*64+rg*16+n16
        #pragma unroll
        for (int rg = 0; rg < 4; rg++)
            #pragma unroll
            for (int c = 0; c < 2; c++) {
                floatx4 acc = MFMA16(kA[0][c], qB[rg][0], fz);
                sC[rg][c] = MFMA16(kA[1][c], qB[rg][1], acc);
            }
        // prefetch next tile's kA during exp/P phase
        if (kt + 1 < NT) loadK(kt + 1, kAn);

        // ---- P^T = exp2(C1) -> shared pt (b64 writes) ----
        #pragma unroll
        for (int rg = 0; rg < 4; rg++)
            #pragma unroll
            for (int c = 0; c < 2; c++) {
                half4 h;
                #pragma unroll
                for (int r = 0; r < 4; r++) h[r] = (_Float16)exp2f(sC[rg][c][r]);
                int q = wn * 64 + rg * 16 + n16;
                *(half4*)&pt[q * PSTR + wm * 32 + c * 16 + quad * 4] = h;
            }
        __syncthreads();   // sync1: P^T visible across wm halves

        // ---- GEMM2: O^T += V^T * P^T ----
        half8 pB[4][2];   // [rg][kd2]: k = key = kd2*32+quad*8+j, n = q
        #pragma unroll
        for (int rg = 0; rg < 4; rg++)
            #pragma unroll
            for (int kd2 = 0; kd2 < 2; kd2++)
                pB[rg][kd2] = *(const half8*)
                    &pt[(wn * 64 + rg * 16 + n16) * PSTR + kd2 * 32 + quad * 8];
        #pragma unroll
        for (int rg = 0; rg < 4; rg++) {
            lsum[rg] = MFMA16(ones, pB[rg][0], lsum[rg]);
            lsum[rg] = MFMA16(ones, pB[rg][1], lsum[rg]);
        }
        #pragma unroll
        for (int rg = 0; rg < 4; rg++)
            #pragma unroll
            for (int c2 = 0; c2 < 2; c2++) {
                oacc[rg][c2] = MFMA16(vA[0][c2], pB[rg][0], oacc[rg][c2]);
                oacc[rg][c2] = MFMA16(vA[1][c2], pB[rg][1], oacc[rg][c2]);
            }
        __syncthreads();   // sync2: pt free for next tile's writes

        #pragma unroll
        for (int kd = 0; kd < 2; kd++)
            #pragma unroll
            for (int c = 0; c < 2; c++) kA[kd][c] = kAn[kd][c];
    }

    // ---- epilogue: normalize (q in lanes), transpose via per-wave scratch ----
    float* scratch = (float*)pt + wave * 576;   // 16 rows x 36 f32, per-wave
    float* Og = Out + headoff + (size_t)qt * BQ * DH;
    const int qr = lane >> 2;
    const int dh = lane & 3;
    #pragma unroll
    for (int rg = 0; rg < 4; rg++) {
        float inv = 1.0f / lsum[rg][0];
        #pragma unroll
        for (int c2 = 0; c2 < 2; c2++) {
            floatx4 v = oacc[rg][c2];
            float4 w = make_float4(v[0] * inv, v[1] * inv, v[2] * inv, v[3] * inv);
            *(float4*)&scratch[n16 * 36 + c2 * 16 + quad * 4] = w;
        }
        float4 r0 = *(const float4*)&scratch[qr * 36 + dh * 8];
        float4 r1 = *(const float4*)&scratch[qr * 36 + dh * 8 + 4];
        int row = wn * 64 + rg * 16 + qr;
        *(float4*)&Og[row * 64 + wm * 32 + dh * 8] = r0;
        *(float4*)&Og[row * 64 + wm * 32 + dh * 8 + 4] = r1;
    }
}

extern "C" void kernel_launch(void* const* d_in, const int* in_sizes, int n_in,
                              void* d_out, int out_size, void* d_ws, size_t ws_size,
                              hipStream_t stream) {
    const float* Q = (const float*)d_in[0];
    const float* K = (const float*)d_in[1];
    const float* V = (const float*)d_in[2];
    const int*  dk = (const int*)d_in[3];
    float* Out = (float*)d_out;

    const int nbh  = in_sizes[0] / (SLEN * DH);      // 32
    const size_t n = (size_t)nbh * SLEN * DH;        // elements per tensor

    _Float16* Kh = (_Float16*)d_ws;                  // n halves
    _Float16* Vt = Kh + n;                           // n halves (needs 4n bytes total)

    const int n8 = (int)(n / 8);
    cvt_k_kernel<<<(n8 + 255) / 256, 256, 0, stream>>>(K, Kh, n8);
    tr_v_kernel<<<nbh * 32, 256, 0, stream>>>(V, Vt);

    dim3 grid(nbh * (SLEN / BQ));                    // 512 flat
    attn_f16_mfma<<<grid, THREADS, 0, stream>>>(Q, Kh, Vt, Out, dk);
}